// Round 7
// baseline (807.417 us; speedup 1.0000x reference)
//
#include <hip/hip_runtime.h>
#include <stdint.h>

#define T_DIM 2048
#define B_DIM 1024
#define A_DIM 4
#define D_DIM 128
#define TC 32
#define NCHUNK (T_DIM / TC)
#define LDH 136                         // Hb row stride (bf16): 68 dwords == 4 mod 32
#define LDC 136                         // Ct staging row stride
#define HB_BYTES (128 * 68 * 4)         // 34816
#define QT_OFF HB_BYTES
#define QT_S 65                         // Qt col stride in dwords (col-major, dword = 2 rows)
#define SMEM_BYTES (QT_OFF + 128 * QT_S * 4)   // 68096 -> 2 blocks/CU

typedef __attribute__((ext_vector_type(8))) short bf16x8;
typedef __attribute__((ext_vector_type(4))) float f32x4;
typedef __attribute__((ext_vector_type(2))) float f32x2;

__device__ __forceinline__ float clampf(float x, float lo, float hi) {
    return fminf(fmaxf(x, lo), hi);
}
__device__ __forceinline__ uint16_t bf16rnd(float f) {
    uint32_t u = __builtin_bit_cast(uint32_t, f) + 0x8000u;
    return (uint16_t)(u >> 16);
}
// pack2(x,y) -> (bf16(y)<<16)|bf16(x): 2 rounding adds + 1 v_perm   [R2-proven]
__device__ __forceinline__ uint32_t pack2(float x, float y) {
    uint32_t ux = __builtin_bit_cast(uint32_t, x) + 0x8000u;
    uint32_t uy = __builtin_bit_cast(uint32_t, y) + 0x8000u;
    return __builtin_amdgcn_perm(uy, ux, 0x07060302);
}
__device__ __forceinline__ float bfLO(uint32_t u) {
    return __builtin_bit_cast(float, u << 16);
}
__device__ __forceinline__ float bfHI(uint32_t u) {
    return __builtin_bit_cast(float, u & 0xFFFF0000u);
}
template <int CTRL>
__device__ __forceinline__ float dppadd(float x) {
    int xi = __builtin_bit_cast(int, x);
    int yi = __builtin_amdgcn_mov_dpp(xi, CTRL, 0xF, 0xF, false);
    return x + __builtin_bit_cast(float, yi);
}
__device__ __forceinline__ float rowsum16(float x) {   // sum over 16-lane DPP rows
    x = dppadd<0x121>(x);
    x = dppadd<0x122>(x);
    x = dppadd<0x124>(x);
    x = dppadd<0x128>(x);
    return x;
}

// One block per b; 4 waves; wave wv owns action a=wv; lane owns d-pair (2*lane, 2*lane+1).
// Structure == R2-passed kernel (590us, absmax 1.0). Deltas vs R2: packed-f32 scan
// updates and acc initialized to beta (both arithmetic identities). Input broadcast
// via v_readlane (R2-proven); NO LDS bc staging (prime suspect of R4/R5 failures).
__global__ __launch_bounds__(256, 2)
void gql_fused(const float* __restrict__ inp,
               const float* __restrict__ phi_raw,
               const float* __restrict__ chi_raw,
               const float* __restrict__ beta_raw,
               const float* __restrict__ kappa_raw,
               const float* __restrict__ C_raw,
               float* __restrict__ out)
{
    __shared__ __attribute__((aligned(16))) char smem[SMEM_BYTES];

    const int b    = blockIdx.x;
    const int tid  = threadIdx.x;
    const int lane = tid & 63;
    const int wv   = tid >> 6;
    const int ml   = lane & 15;
    const int qd   = lane >> 4;

    const int pid = (int)inp[(size_t)b * 9 + 8];

    // ---- scan params (d0 = 2*lane, d0+1) as packed float2
    const int d0 = lane * 2;
    float2 pr = *(const float2*)(phi_raw + (size_t)pid * D_DIM + d0);
    float2 cr = *(const float2*)(chi_raw + (size_t)pid * D_DIM + d0);
    f32x2 phi2, chi2;
    phi2.x = clampf(1.f / (1.f + __expf(-pr.x)), 0.01f, 0.99f);
    phi2.y = clampf(1.f / (1.f + __expf(-pr.y)), 0.01f, 0.99f);
    chi2.x = clampf(1.f / (1.f + __expf(-cr.x)), 0.01f, 0.99f);
    chi2.y = clampf(1.f / (1.f + __expf(-cr.y)), 0.01f, 0.99f);
    f32x2 omphi2 = (f32x2){1.f, 1.f} - phi2;
    f32x2 omchi2 = (f32x2){1.f, 1.f} - chi2;

    // ---- betas in regs; breg[8]=0 is the kappa tile's "beta"
    float breg[9];
    #pragma unroll
    for (int nt = 0; nt < 8; ++nt) {
        float x = beta_raw[(size_t)pid * D_DIM + nt * 16 + ml];
        breg[nt] = clampf(log1pf(__expf(x)), 0.1f, 10.0f);
    }
    breg[8] = 0.f;

    // ---- stage Ct[n][k] = bf16(clip(C[k][n])) into LDS (temporary overlay)
    {
        uint16_t* Ct = (uint16_t*)smem;
        const float* Cp = C_raw + (size_t)pid * (D_DIM * D_DIM);
        #pragma unroll 8
        for (int i = 0; i < 64; ++i) {
            int idx = i * 256 + tid;
            int d = idx >> 7, e = idx & 127;
            Ct[e * LDC + d] = bf16rnd(clampf(Cp[idx], -10.f, 10.f));
        }
        for (int i = tid; i < 16 * LDC; i += 256) {
            int n = i / LDC;
            int k = i - n * LDC;
            float v = (n == 0 && k < D_DIM)
                        ? clampf(kappa_raw[(size_t)pid * D_DIM + k], -10.f, 10.f) : 0.f;
            Ct[(128 + n) * LDC + k] = bf16rnd(v);
        }
    }
    __syncthreads();

    // ---- B-fragments to registers (chunk-invariant)
    bf16x8 bfr[9][4];
    {
        const uint16_t* Ct = (const uint16_t*)smem;
        #pragma unroll
        for (int nt = 0; nt < 9; ++nt)
            #pragma unroll
            for (int kt = 0; kt < 4; ++kt)
                bfr[nt][kt] = *(const bf16x8*)&Ct[(nt * 16 + ml) * LDC + kt * 32 + qd * 8];
    }
    __syncthreads();   // staging overlay now dead

    uint32_t* H32 = (uint32_t*)smem;                         // Hb[m][k-pair]: m*68+dpair
    const uint16_t* Hb16 = (const uint16_t*)smem;
    uint32_t* Qt = (uint32_t*)(smem + QT_OFF);               // col-major, dword = 2 rows

    const int SWt = ((lane >> 4) & 3) << 3;                  // swizzle for cols 2*lane, 2*lane+1

    // ---- per-chunk wave-uniform inputs via readlane: lane l<32 holds step l  [R2-proven]
    float actv, rav;
    {
        size_t t = (size_t)(lane & 31);
        const float* p = inp + (t * B_DIM + b) * 9;
        float a = p[wv], r = p[4 + wv];
        actv = a; rav = a * r;
    }

    f32x2 q01 = (f32x2){0.5f, 0.5f};
    f32x2 h01 = (f32x2){0.f, 0.f};

    for (int chunk = 0; chunk < NCHUNK; ++chunk) {
        const int ai = __builtin_bit_cast(int, actv);
        const int ri = __builtin_bit_cast(int, rav);

        // ---- scan: 32 steps, register-only except paired LDS stores
        uint32_t hw_prev = 0, qwA0 = 0, qwA1 = 0;
        f32x2 q01p = (f32x2){0.f, 0.f};
        #pragma unroll
        for (int tl = 0; tl < TC; ++tl) {
            float sa = __builtin_bit_cast(float, __builtin_amdgcn_readlane(ai, tl));
            float sr = __builtin_bit_cast(float, __builtin_amdgcn_readlane(ri, tl));
            q01 = __builtin_elementwise_fma(omphi2, q01, phi2 * (f32x2){sr, sr});
            h01 = __builtin_elementwise_fma(omchi2, h01, chi2 * (f32x2){sa, sa});
            uint32_t hw = pack2(h01.x, h01.y);
            if (tl & 1) {
                int m = wv * TC + tl - 1;
                H32[m * 68 + lane] = hw_prev;           // rows m, m+1
                H32[(m + 1) * 68 + lane] = hw;
            } else {
                hw_prev = hw;
            }
            if ((tl & 1) == 0) {
                q01p = q01;
            } else if ((tl & 3) == 1) {
                qwA0 = pack2(q01p.x, q01.x);            // col d0, rows tl-1,tl
                qwA1 = pack2(q01p.y, q01.y);            // col d0+1
            } else {                                    // tl&3 == 3
                uint32_t qwB0 = pack2(q01p.x, q01.x);
                uint32_t qwB1 = pack2(q01p.y, q01.y);
                int m2  = wv * 16 + ((tl - 3) >> 1);    // even
                int adw = d0 * QT_S + (m2 ^ SWt);
                Qt[adw]        = qwA0;  Qt[adw + 1]        = qwB0;
                Qt[adw + QT_S] = qwA1;  Qt[adw + QT_S + 1] = qwB1;
            }
        }

        // prefetch next chunk's inputs (latency hidden behind GEMM+epilogue)
        if (chunk + 1 < NCHUNK) {
            size_t t = (size_t)(chunk + 1) * TC + (lane & 31);
            const float* p = inp + (t * B_DIM + b) * 9;
            float a = p[wv], r = p[4 + wv];
            actv = a; rav = a * r;
        }

        // ---- GEMM + epilogue per 16-row m-tile
        #pragma unroll
        for (int mi = 0; mi < 2; ++mi) {
            const int mt = wv * 2 + mi;
            f32x4 acc[9];
            #pragma unroll
            for (int nt = 0; nt < 9; ++nt)
                acc[nt] = (f32x4){breg[nt], breg[nt], breg[nt], breg[nt]};   // +beta for free

            #pragma unroll
            for (int kt = 0; kt < 4; ++kt) {
                bf16x8 afr = *(const bf16x8*)&Hb16[(size_t)(mt * 16 + ml) * LDH + kt * 32 + qd * 8];
                #pragma unroll
                for (int nt = 0; nt < 9; ++nt)
                    acc[nt] = __builtin_amdgcn_mfma_f32_16x16x32_bf16(afr, bfr[nt][kt], acc[nt], 0, 0, 0);
            }

            // kappa tile: col 128 -> ml==0 lanes only (beta=0 there)
            bool km = (ml == 0);
            float p0 = km ? acc[8][0] : 0.f;
            float p1 = km ? acc[8][1] : 0.f;
            float p2 = km ? acc[8][2] : 0.f;
            float p3 = km ? acc[8][3] : 0.f;

            const int m2e = mt * 8 + qd * 2;                // row-pair of rows row0,row0+1
            #pragma unroll
            for (int nt = 0; nt < 8; ++nt) {
                const int SWc = ((nt >> 1) & 3) << 3;       // SW(col=16nt+ml), ml<16
                int adw = (nt * 16 + ml) * QT_S + (m2e ^ SWc);
                uint32_t w0 = Qt[adw];
                uint32_t w1 = Qt[adw + 1];
                p0 = fmaf(acc[nt][0], bfLO(w0), p0);
                p1 = fmaf(acc[nt][1], bfHI(w0), p1);
                p2 = fmaf(acc[nt][2], bfLO(w1), p2);
                p3 = fmaf(acc[nt][3], bfHI(w1), p3);
            }

            p0 = rowsum16(p0);
            p1 = rowsum16(p1);
            p2 = rowsum16(p2);
            p3 = rowsum16(p3);

            if (ml == 0) {
                int row0 = mt * 16 + qd * 4;
                #pragma unroll
                for (int r = 0; r < 4; ++r) {
                    int row = row0 + r;
                    int aa = row >> 5;
                    int tl = row & (TC - 1);
                    size_t t = (size_t)chunk * TC + tl;
                    float pv = (r == 0) ? p0 : (r == 1) ? p1 : (r == 2) ? p2 : p3;
                    out[(t * B_DIM + b) * A_DIM + aa] = pv;
                }
            }
        }
    }

    // ---- final q, h (fp32 state, exact recurrence)
    size_t qbase = (size_t)T_DIM * B_DIM * A_DIM;
    size_t off = (size_t)b * (A_DIM * D_DIM) + (size_t)wv * D_DIM + d0;
    *(float2*)&out[qbase + off] = make_float2(q01.x, q01.y);
    *(float2*)&out[qbase + (size_t)B_DIM * A_DIM * D_DIM + off] = make_float2(h01.x, h01.y);
}

extern "C" void kernel_launch(void* const* d_in, const int* in_sizes, int n_in,
                              void* d_out, int out_size, void* d_ws, size_t ws_size,
                              hipStream_t stream) {
    const float* inp    = (const float*)d_in[0];
    const float* phi_r  = (const float*)d_in[1];
    const float* chi_r  = (const float*)d_in[2];
    const float* beta_r = (const float*)d_in[3];
    const float* kap_r  = (const float*)d_in[4];
    const float* C_r    = (const float*)d_in[5];
    float* outp = (float*)d_out;
    gql_fused<<<dim3(B_DIM), dim3(256), 0, stream>>>(inp, phi_r, chi_r, beta_r, kap_r, C_r, outp);
}